// Round 16
// baseline (193.398 us; speedup 1.0000x reference)
//
#include <hip/hip_runtime.h>
#include <hip/hip_bf16.h>

typedef __attribute__((ext_vector_type(8))) short bf16x8;
typedef __attribute__((ext_vector_type(4))) float f32x4;
typedef unsigned short u16;
typedef unsigned int u32;

__device__ __forceinline__ u16 f2bf(float f) {
    u32 u = __float_as_uint(f);
    u = (u + 0x7FFFu + ((u >> 16) & 1u)) >> 16;
    return (u16)u;
}
__device__ __forceinline__ u32 pk2(float a, float b) {
    return (u32)f2bf(a) | ((u32)f2bf(b) << 16);
}

#define GLDS16(g, l) __builtin_amdgcn_global_load_lds( \
    (const __attribute__((address_space(1))) u32*)(g), \
    (__attribute__((address_space(3))) u32*)(l), 16, 0, 0)

// ---------- centers: cn = c/||c|| bf16 granules [b][kb24][dc4][k256][8]; zeroes den + out ----------
__global__ __launch_bounds__(256) void k_centers(const float* __restrict__ c, u16* __restrict__ cn,
                                                 float* __restrict__ den, float* __restrict__ out) {
    int bid = blockIdx.x;                      // 512 blocks, 4 rows each
    int w = threadIdx.x >> 6, lane = threadIdx.x & 63;
    int row = (bid << 2) + w;                  // b*256 + k
    int b = row >> 8;
    if (bid < 8) den[(bid << 8) + threadIdx.x] = 0.f;
    {   // zero out: 1,572,864 floats / 512 blocks = 3 float4/thread
        float4* o4 = reinterpret_cast<float4*>(out) + (size_t)bid * 768 + threadIdx.x;
        o4[0] = float4{0.f, 0.f, 0.f, 0.f};
        o4[256] = float4{0.f, 0.f, 0.f, 0.f};
        o4[512] = float4{0.f, 0.f, 0.f, 0.f};
    }
    __shared__ u16 rb[4][800];
    const float* src = c + (size_t)row * 768;
    float v[12]; float ss = 0.f;
#pragma unroll
    for (int j = 0; j < 12; ++j) { v[j] = src[lane + (j << 6)]; ss += v[j] * v[j]; }
#pragma unroll
    for (int m = 1; m < 64; m <<= 1) ss += __shfl_xor(ss, m, 64);
    float inv = 1.0f / sqrtf(ss);
#pragma unroll
    for (int j = 0; j < 12; ++j) rb[w][lane + (j << 6)] = f2bf(v[j] * inv);
    __syncthreads();
    int t = threadIdx.x;
    int k0 = (bid << 2) & 255;
#pragma unroll
    for (int p = 0; p < 2; ++p) {
        int idx = (p << 8) + t;
        if (idx < 384) {
            int g = idx >> 2, kr = idx & 3;
            uint4 val = *reinterpret_cast<const uint4*>(&rb[kr][g << 3]);
            int kb = g >> 2, dc = g & 3;
            size_t o = ((((size_t)(b * 24 + kb) << 2) + dc) << 8) + k0 + kr;
            *reinterpret_cast<uint4*>(cn + (o << 3)) = val;
        }
    }
}

// ---------- GEMM1: BK=64 (R15) + xbf emission (packed bf16 already in regs -> free writes) ----------
__global__ __launch_bounds__(256, 2) void k_gemm1(const float* __restrict__ x, const u16* __restrict__ cn,
                                                  u16* __restrict__ probT, float* __restrict__ den,
                                                  u16* __restrict__ xbf) {
    const int b = blockIdx.y;
    const int n0 = blockIdx.x << 7;            // 128-token tile
    const int t = threadIdx.x;
    const int wave = t >> 6, lane = t & 63;
    const int lg = lane >> 4, lr = lane & 15;
    const int wm = wave >> 1, wk = wave & 1;
    const int tok0 = wm << 6;                  // wave token base (0/64)
    const int kb0 = wk << 7;                   // wave K base (0/128)

    __shared__ union {
        struct {
            u16 A[8][130][8];                  // 16640 B: plane stride 2080B (=8 mod 32 dw)
            u16 B[2][4][256][8];               // 32768 B: [d-half][dc][k][8], GLDS-linear
        } s;
        u16 T[256][136];                       // 69632 B transpose staging
    } u;
    __shared__ float inv_s[128];
    __shared__ float ksum[2][128];
    __shared__ float denp[256];

    denp[t] = 0.f;

    f32x4 acc[8][4];
#pragma unroll
    for (int kf = 0; kf < 8; ++kf)
#pragma unroll
        for (int tf = 0; tf < 4; ++tf) acc[kf][tf] = (f32x4){0.f, 0.f, 0.f, 0.f};

    const char* cnb = (const char*)(cn + (size_t)b * 24 * 4 * 256 * 8);
    const int tokS = ((t >> 1) & 63) + ((t >> 7) << 6);   // 0..127
    const int dcS = t & 1;                                 // 32-d half of the 64-d K-step
    const float* ap = x + ((size_t)b * 8192 + n0 + tokS) * 768 + (dcS << 5);
    u16* xout = xbf + ((size_t)b * 8192 + n0 + tokS) * 768 + (dcS << 5);

    float sq = 0.f;

    for (int it = 0; it < 12; ++it) {
        // ---- load A to regs (128B contiguous per thread) + issue B GLDS ----
        const float* p = ap + (it << 6);
        float4 f[8];
#pragma unroll
        for (int j = 0; j < 8; ++j) f[j] = *reinterpret_cast<const float4*>(p + (j << 2));
        // B: two 16KB halves; each wave stages 4KB per half (4 GLDS x 1KB)
#pragma unroll
        for (int h = 0; h < 2; ++h) {
            const char* src = cnb + (size_t)((it << 1) + h) * 16384 + (wave << 12) + (lane << 4);
            char* dst = (char*)&u.s.B[h][0][0][0] + (wave << 12);
            GLDS16(src, dst);
            GLDS16(src + 1024, dst + 1024);
            GLDS16(src + 2048, dst + 2048);
            GLDS16(src + 3072, dst + 3072);
        }
        // ---- stage A (bf16 pack + sum of squares) + persist bf16 x for gemm2 ----
#pragma unroll
        for (int j = 0; j < 8; ++j)
            sq += f[j].x * f[j].x + f[j].y * f[j].y + f[j].z * f[j].z + f[j].w * f[j].w;
        uint4 w[4];
#pragma unroll
        for (int j = 0; j < 4; ++j)
            w[j] = make_uint4(pk2(f[2 * j].x, f[2 * j].y), pk2(f[2 * j].z, f[2 * j].w),
                              pk2(f[2 * j + 1].x, f[2 * j + 1].y), pk2(f[2 * j + 1].z, f[2 * j + 1].w));
#pragma unroll
        for (int j = 0; j < 4; ++j)
            *reinterpret_cast<uint4*>(&u.s.A[(dcS << 2) + j][tokS][0]) = w[j];
        u16* xo = xout + (it << 6);            // 64B contiguous per thread
#pragma unroll
        for (int j = 0; j < 4; ++j)
            *reinterpret_cast<uint4*>(xo + (j << 3)) = w[j];
        __syncthreads();   // GLDS + ds_write visible

        // ---- 64 MFMA over the 64-d K-step ----
        bf16x8 a[4][2];
#pragma unroll
        for (int tf = 0; tf < 4; ++tf)
#pragma unroll
            for (int h = 0; h < 2; ++h)
                a[tf][h] = *reinterpret_cast<const bf16x8*>(&u.s.A[(h << 2) + lg][tok0 + (tf << 4) + lr][0]);
#pragma unroll
        for (int kf = 0; kf < 8; ++kf) {
#pragma unroll
            for (int h = 0; h < 2; ++h) {
                bf16x8 bb = *reinterpret_cast<const bf16x8*>(&u.s.B[h][lg][kb0 + (kf << 4) + lr][0]);
#pragma unroll
                for (int tf = 0; tf < 4; ++tf)
                    acc[kf][tf] = __builtin_amdgcn_mfma_f32_16x16x32_bf16(a[tf][h], bb, acc[kf][tf], 0, 0, 0);
            }
        }
        __syncthreads();   // compute done before next overwrite
    }

    // inverse norms (thread pair t^1 holds the complementary d-half)
    sq += __shfl_xor(sq, 1, 64);
    if ((t & 1) == 0) inv_s[tokS] = 1.0f / sqrtf(sq);
    __syncthreads();

    float iv[4][4];
#pragma unroll
    for (int tf = 0; tf < 4; ++tf)
#pragma unroll
        for (int r = 0; r < 4; ++r)
            iv[tf][r] = inv_s[tok0 + (tf << 4) + (lg << 2) + r];

    // exp (bounded logits, no max-subtract) + per-token partial sums over this wave's 128 K
    float rowsum[4][4];
#pragma unroll
    for (int tf = 0; tf < 4; ++tf)
#pragma unroll
        for (int r = 0; r < 4; ++r) rowsum[tf][r] = 0.f;
#pragma unroll
    for (int kf = 0; kf < 8; ++kf)
#pragma unroll
        for (int tf = 0; tf < 4; ++tf)
#pragma unroll
            for (int r = 0; r < 4; ++r) {
                float e = __expf(acc[kf][tf][r] * iv[tf][r]);
                acc[kf][tf][r] = e; rowsum[tf][r] += e;
            }
#pragma unroll
    for (int tf = 0; tf < 4; ++tf)
#pragma unroll
        for (int r = 0; r < 4; ++r) {
#pragma unroll
            for (int m = 1; m < 16; m <<= 1) rowsum[tf][r] += __shfl_xor(rowsum[tf][r], m, 64);
        }
    if (lr == 0) {
#pragma unroll
        for (int tf = 0; tf < 4; ++tf)
#pragma unroll
            for (int r = 0; r < 4; ++r)
                ksum[wk][tok0 + (tf << 4) + (lg << 2) + r] = rowsum[tf][r];
    }
    __syncthreads();

    float rs[4][4];
#pragma unroll
    for (int tf = 0; tf < 4; ++tf)
#pragma unroll
        for (int r = 0; r < 4; ++r) {
            int idx = tok0 + (tf << 4) + (lg << 2) + r;
            rs[tf][r] = 1.0f / (ksum[0][idx] + ksum[1][idx]);
        }

    // prob, den column sums, transpose into LDS T[K][token]
    float dcol[8];
#pragma unroll
    for (int kf = 0; kf < 8; ++kf) dcol[kf] = 0.f;
#pragma unroll
    for (int kf = 0; kf < 8; ++kf)
#pragma unroll
        for (int tf = 0; tf < 4; ++tf)
#pragma unroll
            for (int r = 0; r < 4; ++r) {
                float p = acc[kf][tf][r] * rs[tf][r];
                acc[kf][tf][r] = p; dcol[kf] += p;
            }
#pragma unroll
    for (int kf = 0; kf < 8; ++kf) {
        dcol[kf] += __shfl_xor(dcol[kf], 16, 64);
        dcol[kf] += __shfl_xor(dcol[kf], 32, 64);
    }
    if (lg == 0) {
#pragma unroll
        for (int kf = 0; kf < 8; ++kf) atomicAdd(&denp[kb0 + (kf << 4) + lr], dcol[kf]);
    }
#pragma unroll
    for (int kf = 0; kf < 8; ++kf)
#pragma unroll
        for (int tf = 0; tf < 4; ++tf)
            *reinterpret_cast<ushort4*>(&u.T[kb0 + (kf << 4) + lr][tok0 + (tf << 4) + (lg << 2)]) =
                make_ushort4(f2bf(acc[kf][tf][0]), f2bf(acc[kf][tf][1]),
                             f2bf(acc[kf][tf][2]), f2bf(acc[kf][tf][3]));
    __syncthreads();

    // coalesced writeout of probT tile [256][128]
    u16* pTb = probT + (size_t)b * 256 * 8192 + n0;
#pragma unroll
    for (int i = 0; i < 16; ++i) {
        int idx = (i << 8) + t;
        int row = idx >> 4, ch = idx & 15;
        *reinterpret_cast<uint4*>(pTb + (size_t)row * 8192 + (ch << 3)) =
            *reinterpret_cast<const uint4*>(&u.T[row][ch << 3]);
    }
    atomicAdd(&den[(b << 8) + t], denp[t]);
}

// ---------- GEMM2+finalize fused: bf16 x reads (half fetch, no cvt), HW f32 atomics ----------
__global__ __launch_bounds__(256) void k_gemm2(const u16* __restrict__ xbf, const u16* __restrict__ probT,
                                               const float* __restrict__ den, float* __restrict__ out) {
    const int bid = blockIdx.x;                // 768 blocks
    const int xcd = bid & 7, slot = bid >> 3;
    const int orig = xcd * 96 + slot;
    const int dt = orig % 12, sb = orig / 12;  // 12 d-tiles of one (s,b) share an XCD
    const int s = sb >> 3, b = sb & 7;
    const int d0 = dt << 6;
    const int t = threadIdx.x;
    const int wave = t >> 6, lane = t & 63;
    const int lg = lane >> 4, lr = lane & 15;

    f32x4 acc[4][4];
#pragma unroll
    for (int m = 0; m < 4; ++m)
#pragma unroll
        for (int tt = 0; tt < 4; ++tt) acc[m][tt] = (f32x4){0.f, 0.f, 0.f, 0.f};

    const int n0 = s << 10;
    const u16* pA = probT + (size_t)b * 256 * 8192;
    const u16* xB = xbf + (size_t)b * 8192 * 768;

    for (int kb = 0; kb < 32; ++kb) {
        int nbase = n0 + (kb << 5);
        bf16x8 a[4];
#pragma unroll
        for (int m = 0; m < 4; ++m) {
            int k = (wave << 6) + (m << 4) + lr;
            a[m] = *reinterpret_cast<const bf16x8*>(pA + (size_t)k * 8192 + nbase + (lg << 3));
        }
        const u16* xr = xB + (size_t)(nbase + (lg << 3)) * 768 + d0 + lr;
        bf16x8 bb[4];
#pragma unroll
        for (int tt = 0; tt < 4; ++tt)
#pragma unroll
            for (int j = 0; j < 8; ++j)
                bb[tt][j] = (short)xr[(size_t)j * 768 + (tt << 4)];
#pragma unroll
        for (int m = 0; m < 4; ++m)
#pragma unroll
            for (int tt = 0; tt < 4; ++tt)
                acc[m][tt] = __builtin_amdgcn_mfma_f32_16x16x32_bf16(a[m], bb[tt], acc[m][tt], 0, 0, 0);
    }

    // fused epilogue: scale by 1/(den+eps), accumulate into out with HW f32 atomics
    float* ob = out + (size_t)(b << 8) * 768;
#pragma unroll
    for (int m = 0; m < 4; ++m) {
        int kb_ = (wave << 6) + (m << 4) + (lg << 2);
#pragma unroll
        for (int reg = 0; reg < 4; ++reg) {
            float dv = 1.0f / (den[(b << 8) + kb_ + reg] + 1e-8f);
#pragma unroll
            for (int tt = 0; tt < 4; ++tt)
                unsafeAtomicAdd(&ob[(size_t)(kb_ + reg) * 768 + d0 + (tt << 4) + lr],
                                acc[m][tt][reg] * dv);
        }
    }
}

extern "C" void kernel_launch(void* const* d_in, const int* in_sizes, int n_in,
                              void* d_out, int out_size, void* d_ws, size_t ws_size,
                              hipStream_t stream) {
    const float* x = (const float*)d_in[0];
    const float* centers = (const float*)d_in[1];
    float* out = (float*)d_out;
    char* ws = (char*)d_ws;
    u16* cn       = (u16*)ws;                    //   3,145,728 B
    u16* probT    = (u16*)(ws + 3145728);        //  33,554,432 B
    float* den    = (float*)(ws + 36700160);     //       8,192 B
    u16* xbf      = (u16*)(ws + 36708352);       // 100,663,296 B  (total ~137 MB)

    k_centers<<<512, 256, 0, stream>>>(centers, cn, den, out);
    k_gemm1<<<dim3(64, 8), 256, 0, stream>>>(x, cn, probT, den, xbf);
    k_gemm2<<<768, 256, 0, stream>>>(xbf, probT, den, out);
}

// Round 17
// 164.058 us; speedup vs baseline: 1.1788x; 1.1788x over previous
//
#include <hip/hip_runtime.h>
#include <hip/hip_bf16.h>

typedef __attribute__((ext_vector_type(8))) short bf16x8;
typedef __attribute__((ext_vector_type(4))) float f32x4;
typedef unsigned short u16;
typedef unsigned int u32;

__device__ __forceinline__ u16 f2bf(float f) {
    u32 u = __float_as_uint(f);
    u = (u + 0x7FFFu + ((u >> 16) & 1u)) >> 16;
    return (u16)u;
}
__device__ __forceinline__ u32 pk2(float a, float b) {
    return (u32)f2bf(a) | ((u32)f2bf(b) << 16);
}

#define GLDS16(g, l) __builtin_amdgcn_global_load_lds( \
    (const __attribute__((address_space(1))) u32*)(g), \
    (__attribute__((address_space(3))) u32*)(l), 16, 0, 0)

// ---------- centers: cn = c/||c|| bf16 granules [b][kb24][dc4][k256][8]; zeroes den + out ----------
__global__ __launch_bounds__(256) void k_centers(const float* __restrict__ c, u16* __restrict__ cn,
                                                 float* __restrict__ den, float* __restrict__ out) {
    int bid = blockIdx.x;                      // 512 blocks, 4 rows each
    int w = threadIdx.x >> 6, lane = threadIdx.x & 63;
    int row = (bid << 2) + w;                  // b*256 + k
    int b = row >> 8;
    if (bid < 8) den[(bid << 8) + threadIdx.x] = 0.f;
    {   // zero out: 1,572,864 floats / 512 blocks = 3 float4/thread
        float4* o4 = reinterpret_cast<float4*>(out) + (size_t)bid * 768 + threadIdx.x;
        o4[0] = float4{0.f, 0.f, 0.f, 0.f};
        o4[256] = float4{0.f, 0.f, 0.f, 0.f};
        o4[512] = float4{0.f, 0.f, 0.f, 0.f};
    }
    __shared__ u16 rb[4][800];
    const float* src = c + (size_t)row * 768;
    float v[12]; float ss = 0.f;
#pragma unroll
    for (int j = 0; j < 12; ++j) { v[j] = src[lane + (j << 6)]; ss += v[j] * v[j]; }
#pragma unroll
    for (int m = 1; m < 64; m <<= 1) ss += __shfl_xor(ss, m, 64);
    float inv = 1.0f / sqrtf(ss);
#pragma unroll
    for (int j = 0; j < 12; ++j) rb[w][lane + (j << 6)] = f2bf(v[j] * inv);
    __syncthreads();
    int t = threadIdx.x;
    int k0 = (bid << 2) & 255;
#pragma unroll
    for (int p = 0; p < 2; ++p) {
        int idx = (p << 8) + t;
        if (idx < 384) {
            int g = idx >> 2, kr = idx & 3;
            uint4 val = *reinterpret_cast<const uint4*>(&rb[kr][g << 3]);
            int kb = g >> 2, dc = g & 3;
            size_t o = ((((size_t)(b * 24 + kb) << 2) + dc) << 8) + k0 + kr;
            *reinterpret_cast<uint4*>(cn + (o << 3)) = val;
        }
    }
}

// ---------- GEMM1: BK=64, 12 convoys, A prefetched one convoy ahead (fE/fO ping-pong) ----------
__global__ __launch_bounds__(256, 2) void k_gemm1(const float* __restrict__ x, const u16* __restrict__ cn,
                                                  u16* __restrict__ probT, float* __restrict__ den) {
    const int b = blockIdx.y;
    const int n0 = blockIdx.x << 7;            // 128-token tile
    const int t = threadIdx.x;
    const int wave = t >> 6, lane = t & 63;
    const int lg = lane >> 4, lr = lane & 15;
    const int wm = wave >> 1, wk = wave & 1;
    const int tok0 = wm << 6;                  // wave token base (0/64)
    const int kb0 = wk << 7;                   // wave K base (0/128)

    __shared__ union {
        struct {
            u16 A[8][130][8];                  // 16640 B: plane stride 2080B (=8 mod 32 dw)
            u16 B[2][4][256][8];               // 32768 B: [d-half][dc][k][8], GLDS-linear
        } s;
        u16 T[256][136];                       // 69632 B transpose staging
    } u;
    __shared__ float inv_s[128];
    __shared__ float ksum[2][128];
    __shared__ float denp[256];

    denp[t] = 0.f;

    f32x4 acc[8][4];
#pragma unroll
    for (int kf = 0; kf < 8; ++kf)
#pragma unroll
        for (int tf = 0; tf < 4; ++tf) acc[kf][tf] = (f32x4){0.f, 0.f, 0.f, 0.f};

    const char* cnb = (const char*)(cn + (size_t)b * 24 * 4 * 256 * 8);
    const int tokS = ((t >> 1) & 63) + ((t >> 7) << 6);   // 0..127
    const int dcS = t & 1;                                 // 32-d half of the 64-d K-step
    const float* ap = x + ((size_t)b * 8192 + n0 + tokS) * 768 + (dcS << 5);

    float sq = 0.f;

    auto loadA = [&](int it2, float4* ff) {
        const float* p = ap + (it2 << 6);
#pragma unroll
        for (int j = 0; j < 8; ++j) ff[j] = *reinterpret_cast<const float4*>(p + (j << 2));
    };
    auto issueB = [&](int it2) {
#pragma unroll
        for (int h = 0; h < 2; ++h) {
            const char* src = cnb + (size_t)((it2 << 1) + h) * 16384 + (wave << 12) + (lane << 4);
            char* dst = (char*)&u.s.B[h][0][0][0] + (wave << 12);
            GLDS16(src, dst);
            GLDS16(src + 1024, dst + 1024);
            GLDS16(src + 2048, dst + 2048);
            GLDS16(src + 3072, dst + 3072);
        }
    };
    auto packA = [&](float4* ff) {
#pragma unroll
        for (int j = 0; j < 8; ++j)
            sq += ff[j].x * ff[j].x + ff[j].y * ff[j].y + ff[j].z * ff[j].z + ff[j].w * ff[j].w;
#pragma unroll
        for (int j = 0; j < 4; ++j) {
            *reinterpret_cast<uint4*>(&u.s.A[(dcS << 2) + j][tokS][0]) =
                make_uint4(pk2(ff[2 * j].x, ff[2 * j].y), pk2(ff[2 * j].z, ff[2 * j].w),
                           pk2(ff[2 * j + 1].x, ff[2 * j + 1].y), pk2(ff[2 * j + 1].z, ff[2 * j + 1].w));
        }
    };
    auto mfmaStep = [&]() {
        bf16x8 a[4][2];
#pragma unroll
        for (int tf = 0; tf < 4; ++tf)
#pragma unroll
            for (int h = 0; h < 2; ++h)
                a[tf][h] = *reinterpret_cast<const bf16x8*>(&u.s.A[(h << 2) + lg][tok0 + (tf << 4) + lr][0]);
#pragma unroll
        for (int kf = 0; kf < 8; ++kf) {
#pragma unroll
            for (int h = 0; h < 2; ++h) {
                bf16x8 bb = *reinterpret_cast<const bf16x8*>(&u.s.B[h][lg][kb0 + (kf << 4) + lr][0]);
#pragma unroll
                for (int tf = 0; tf < 4; ++tf)
                    acc[kf][tf] = __builtin_amdgcn_mfma_f32_16x16x32_bf16(a[tf][h], bb, acc[kf][tf], 0, 0, 0);
            }
        }
    };

    float4 fE[8], fO[8];
    loadA(0, fE);
    for (int it = 0; it < 12; it += 2) {
        // sub-iter it (A in fE)
        issueB(it);
        packA(fE);
        __syncthreads();                       // GLDS + ds_write visible
        loadA(it + 1, fO);                     // prefetch next A under MFMA
        mfmaStep();
        __syncthreads();                       // reads done before overwrite

        // sub-iter it+1 (A in fO)
        issueB(it + 1);
        packA(fO);
        __syncthreads();
        if (it < 10) loadA(it + 2, fE);
        mfmaStep();
        __syncthreads();
    }

    // inverse norms (thread pair t^1 holds the complementary d-half)
    sq += __shfl_xor(sq, 1, 64);
    if ((t & 1) == 0) inv_s[tokS] = 1.0f / sqrtf(sq);
    __syncthreads();

    float iv[4][4];
#pragma unroll
    for (int tf = 0; tf < 4; ++tf)
#pragma unroll
        for (int r = 0; r < 4; ++r)
            iv[tf][r] = inv_s[tok0 + (tf << 4) + (lg << 2) + r];

    // exp (bounded logits, no max-subtract) + per-token partial sums over this wave's 128 K
    float rowsum[4][4];
#pragma unroll
    for (int tf = 0; tf < 4; ++tf)
#pragma unroll
        for (int r = 0; r < 4; ++r) rowsum[tf][r] = 0.f;
#pragma unroll
    for (int kf = 0; kf < 8; ++kf)
#pragma unroll
        for (int tf = 0; tf < 4; ++tf)
#pragma unroll
            for (int r = 0; r < 4; ++r) {
                float e = __expf(acc[kf][tf][r] * iv[tf][r]);
                acc[kf][tf][r] = e; rowsum[tf][r] += e;
            }
#pragma unroll
    for (int tf = 0; tf < 4; ++tf)
#pragma unroll
        for (int r = 0; r < 4; ++r) {
#pragma unroll
            for (int m = 1; m < 16; m <<= 1) rowsum[tf][r] += __shfl_xor(rowsum[tf][r], m, 64);
        }
    if (lr == 0) {
#pragma unroll
        for (int tf = 0; tf < 4; ++tf)
#pragma unroll
            for (int r = 0; r < 4; ++r)
                ksum[wk][tok0 + (tf << 4) + (lg << 2) + r] = rowsum[tf][r];
    }
    __syncthreads();

    float rs[4][4];
#pragma unroll
    for (int tf = 0; tf < 4; ++tf)
#pragma unroll
        for (int r = 0; r < 4; ++r) {
            int idx = tok0 + (tf << 4) + (lg << 2) + r;
            rs[tf][r] = 1.0f / (ksum[0][idx] + ksum[1][idx]);
        }

    // prob, den column sums, transpose into LDS T[K][token]
    float dcol[8];
#pragma unroll
    for (int kf = 0; kf < 8; ++kf) dcol[kf] = 0.f;
#pragma unroll
    for (int kf = 0; kf < 8; ++kf)
#pragma unroll
        for (int tf = 0; tf < 4; ++tf)
#pragma unroll
            for (int r = 0; r < 4; ++r) {
                float p = acc[kf][tf][r] * rs[tf][r];
                acc[kf][tf][r] = p; dcol[kf] += p;
            }
#pragma unroll
    for (int kf = 0; kf < 8; ++kf) {
        dcol[kf] += __shfl_xor(dcol[kf], 16, 64);
        dcol[kf] += __shfl_xor(dcol[kf], 32, 64);
    }
    if (lg == 0) {
#pragma unroll
        for (int kf = 0; kf < 8; ++kf) atomicAdd(&denp[kb0 + (kf << 4) + lr], dcol[kf]);
    }
#pragma unroll
    for (int kf = 0; kf < 8; ++kf)
#pragma unroll
        for (int tf = 0; tf < 4; ++tf)
            *reinterpret_cast<ushort4*>(&u.T[kb0 + (kf << 4) + lr][tok0 + (tf << 4) + (lg << 2)]) =
                make_ushort4(f2bf(acc[kf][tf][0]), f2bf(acc[kf][tf][1]),
                             f2bf(acc[kf][tf][2]), f2bf(acc[kf][tf][3]));
    __syncthreads();

    // coalesced writeout of probT tile [256][128]
    u16* pTb = probT + (size_t)b * 256 * 8192 + n0;
#pragma unroll
    for (int i = 0; i < 16; ++i) {
        int idx = (i << 8) + t;
        int row = idx >> 4, ch = idx & 15;
        *reinterpret_cast<uint4*>(pTb + (size_t)row * 8192 + (ch << 3)) =
            *reinterpret_cast<const uint4*>(&u.T[row][ch << 3]);
    }
    atomicAdd(&den[(b << 8) + t], denp[t]);
}

// ---------- GEMM2+finalize fused (R15-exact): out += acc/(den+eps) via native f32 atomics ----------
__global__ __launch_bounds__(256) void k_gemm2(const float* __restrict__ x, const u16* __restrict__ probT,
                                               const float* __restrict__ den, float* __restrict__ out) {
    const int bid = blockIdx.x;                // 768 blocks
    const int xcd = bid & 7, slot = bid >> 3;
    const int orig = xcd * 96 + slot;
    const int dt = orig % 12, sb = orig / 12;  // 12 d-tiles of one (s,b) share an XCD
    const int s = sb >> 3, b = sb & 7;
    const int d0 = dt << 6;
    const int t = threadIdx.x;
    const int wave = t >> 6, lane = t & 63;
    const int lg = lane >> 4, lr = lane & 15;

    f32x4 acc[4][4];
#pragma unroll
    for (int m = 0; m < 4; ++m)
#pragma unroll
        for (int tt = 0; tt < 4; ++tt) acc[m][tt] = (f32x4){0.f, 0.f, 0.f, 0.f};

    const int n0 = s << 10;
    const u16* pA = probT + (size_t)b * 256 * 8192;
    const float* xB = x + (size_t)b * 8192 * 768;

    for (int kb = 0; kb < 32; ++kb) {
        int nbase = n0 + (kb << 5);
        bf16x8 a[4];
#pragma unroll
        for (int m = 0; m < 4; ++m) {
            int k = (wave << 6) + (m << 4) + lr;
            a[m] = *reinterpret_cast<const bf16x8*>(pA + (size_t)k * 8192 + nbase + (lg << 3));
        }
        const float* xr = xB + (size_t)(nbase + (lg << 3)) * 768 + d0 + lr;
        bf16x8 bb[4];
#pragma unroll
        for (int tt = 0; tt < 4; ++tt)
#pragma unroll
            for (int j = 0; j < 8; ++j) {
                float f = xr[(size_t)j * 768 + (tt << 4)];
                bb[tt][j] = (short)f2bf(f);
            }
#pragma unroll
        for (int m = 0; m < 4; ++m)
#pragma unroll
            for (int tt = 0; tt < 4; ++tt)
                acc[m][tt] = __builtin_amdgcn_mfma_f32_16x16x32_bf16(a[m], bb[tt], acc[m][tt], 0, 0, 0);
    }

    // fused epilogue: scale by 1/(den+eps), accumulate into out with HW f32 atomics
    float* ob = out + (size_t)(b << 8) * 768;
#pragma unroll
    for (int m = 0; m < 4; ++m) {
        int kb_ = (wave << 6) + (m << 4) + (lg << 2);
#pragma unroll
        for (int reg = 0; reg < 4; ++reg) {
            float dv = 1.0f / (den[(b << 8) + kb_ + reg] + 1e-8f);
#pragma unroll
            for (int tt = 0; tt < 4; ++tt)
                unsafeAtomicAdd(&ob[(size_t)(kb_ + reg) * 768 + d0 + (tt << 4) + lr],
                                acc[m][tt][reg] * dv);
        }
    }
}

extern "C" void kernel_launch(void* const* d_in, const int* in_sizes, int n_in,
                              void* d_out, int out_size, void* d_ws, size_t ws_size,
                              hipStream_t stream) {
    const float* x = (const float*)d_in[0];
    const float* centers = (const float*)d_in[1];
    float* out = (float*)d_out;
    char* ws = (char*)d_ws;
    u16* cn       = (u16*)ws;                    //  3,145,728 B
    u16* probT    = (u16*)(ws + 3145728);        // 33,554,432 B
    float* den    = (float*)(ws + 36700160);     //      8,192 B  (total ~37 MB)

    k_centers<<<512, 256, 0, stream>>>(centers, cn, den, out);
    k_gemm1<<<dim3(64, 8), 256, 0, stream>>>(x, cn, probT, den);
    k_gemm2<<<768, 256, 0, stream>>>(x, probT, den, out);
}

// Round 18
// 159.820 us; speedup vs baseline: 1.2101x; 1.0265x over previous
//
#include <hip/hip_runtime.h>
#include <hip/hip_bf16.h>

typedef __attribute__((ext_vector_type(8))) short bf16x8;
typedef __attribute__((ext_vector_type(4))) float f32x4;
typedef unsigned short u16;
typedef unsigned int u32;

__device__ __forceinline__ u16 f2bf(float f) {
    u32 u = __float_as_uint(f);
    u = (u + 0x7FFFu + ((u >> 16) & 1u)) >> 16;
    return (u16)u;
}
__device__ __forceinline__ u32 pk2(float a, float b) {
    return (u32)f2bf(a) | ((u32)f2bf(b) << 16);
}

#define GLDS16(g, l) __builtin_amdgcn_global_load_lds( \
    (const __attribute__((address_space(1))) u32*)(g), \
    (__attribute__((address_space(3))) u32*)(l), 16, 0, 0)

// ---------- centers: cn = c/||c|| bf16 granules [b][kb24][dc4][k256][8]; zeroes den + out ----------
__global__ __launch_bounds__(256) void k_centers(const float* __restrict__ c, u16* __restrict__ cn,
                                                 float* __restrict__ den, float* __restrict__ out) {
    int bid = blockIdx.x;                      // 512 blocks, 4 rows each
    int w = threadIdx.x >> 6, lane = threadIdx.x & 63;
    int row = (bid << 2) + w;                  // b*256 + k
    int b = row >> 8;
    if (bid < 8) den[(bid << 8) + threadIdx.x] = 0.f;
    {   // zero out: 1,572,864 floats / 512 blocks = 3 float4/thread
        float4* o4 = reinterpret_cast<float4*>(out) + (size_t)bid * 768 + threadIdx.x;
        o4[0] = float4{0.f, 0.f, 0.f, 0.f};
        o4[256] = float4{0.f, 0.f, 0.f, 0.f};
        o4[512] = float4{0.f, 0.f, 0.f, 0.f};
    }
    __shared__ u16 rb[4][800];
    const float* src = c + (size_t)row * 768;
    float v[12]; float ss = 0.f;
#pragma unroll
    for (int j = 0; j < 12; ++j) { v[j] = src[lane + (j << 6)]; ss += v[j] * v[j]; }
#pragma unroll
    for (int m = 1; m < 64; m <<= 1) ss += __shfl_xor(ss, m, 64);
    float inv = 1.0f / sqrtf(ss);
#pragma unroll
    for (int j = 0; j < 12; ++j) rb[w][lane + (j << 6)] = f2bf(v[j] * inv);
    __syncthreads();
    int t = threadIdx.x;
    int k0 = (bid << 2) & 255;
#pragma unroll
    for (int p = 0; p < 2; ++p) {
        int idx = (p << 8) + t;
        if (idx < 384) {
            int g = idx >> 2, kr = idx & 3;
            uint4 val = *reinterpret_cast<const uint4*>(&rb[kr][g << 3]);
            int kb = g >> 2, dc = g & 3;
            size_t o = ((((size_t)(b * 24 + kb) << 2) + dc) << 8) + k0 + kr;
            *reinterpret_cast<uint4*>(cn + (o << 3)) = val;
        }
    }
}

// ---------- GEMM1: BK=64, 12 single-buffered convoys (R15-exact) ----------
__global__ __launch_bounds__(256, 2) void k_gemm1(const float* __restrict__ x, const u16* __restrict__ cn,
                                                  u16* __restrict__ probT, float* __restrict__ den) {
    const int b = blockIdx.y;
    const int n0 = blockIdx.x << 7;            // 128-token tile
    const int t = threadIdx.x;
    const int wave = t >> 6, lane = t & 63;
    const int lg = lane >> 4, lr = lane & 15;
    const int wm = wave >> 1, wk = wave & 1;
    const int tok0 = wm << 6;                  // wave token base (0/64)
    const int kb0 = wk << 7;                   // wave K base (0/128)

    __shared__ union {
        struct {
            u16 A[8][130][8];                  // 16640 B: plane stride 2080B (=8 mod 32 dw)
            u16 B[2][4][256][8];               // 32768 B: [d-half][dc][k][8], GLDS-linear
        } s;
        u16 T[256][136];                       // 69632 B transpose staging
    } u;
    __shared__ float inv_s[128];
    __shared__ float ksum[2][128];
    __shared__ float denp[256];

    denp[t] = 0.f;

    f32x4 acc[8][4];
#pragma unroll
    for (int kf = 0; kf < 8; ++kf)
#pragma unroll
        for (int tf = 0; tf < 4; ++tf) acc[kf][tf] = (f32x4){0.f, 0.f, 0.f, 0.f};

    const char* cnb = (const char*)(cn + (size_t)b * 24 * 4 * 256 * 8);
    const int tokS = ((t >> 1) & 63) + ((t >> 7) << 6);   // 0..127
    const int dcS = t & 1;                                 // 32-d half of the 64-d K-step
    const float* ap = x + ((size_t)b * 8192 + n0 + tokS) * 768 + (dcS << 5);

    float sq = 0.f;

    for (int it = 0; it < 12; ++it) {
        // ---- load A to regs (128B contiguous per thread) + issue B GLDS ----
        const float* p = ap + (it << 6);
        float4 f[8];
#pragma unroll
        for (int j = 0; j < 8; ++j) f[j] = *reinterpret_cast<const float4*>(p + (j << 2));
        // B: two 16KB halves; each wave stages 4KB per half (4 GLDS x 1KB)
#pragma unroll
        for (int h = 0; h < 2; ++h) {
            const char* src = cnb + (size_t)((it << 1) + h) * 16384 + (wave << 12) + (lane << 4);
            char* dst = (char*)&u.s.B[h][0][0][0] + (wave << 12);
            GLDS16(src, dst);
            GLDS16(src + 1024, dst + 1024);
            GLDS16(src + 2048, dst + 2048);
            GLDS16(src + 3072, dst + 3072);
        }
        // ---- stage A (bf16 pack + sum of squares) ----
#pragma unroll
        for (int j = 0; j < 8; ++j)
            sq += f[j].x * f[j].x + f[j].y * f[j].y + f[j].z * f[j].z + f[j].w * f[j].w;
#pragma unroll
        for (int j = 0; j < 4; ++j) {
            *reinterpret_cast<uint4*>(&u.s.A[(dcS << 2) + j][tokS][0]) =
                make_uint4(pk2(f[2 * j].x, f[2 * j].y), pk2(f[2 * j].z, f[2 * j].w),
                           pk2(f[2 * j + 1].x, f[2 * j + 1].y), pk2(f[2 * j + 1].z, f[2 * j + 1].w));
        }
        __syncthreads();   // GLDS + ds_write visible

        // ---- 64 MFMA over the 64-d K-step ----
        bf16x8 a[4][2];
#pragma unroll
        for (int tf = 0; tf < 4; ++tf)
#pragma unroll
            for (int h = 0; h < 2; ++h)
                a[tf][h] = *reinterpret_cast<const bf16x8*>(&u.s.A[(h << 2) + lg][tok0 + (tf << 4) + lr][0]);
#pragma unroll
        for (int kf = 0; kf < 8; ++kf) {
#pragma unroll
            for (int h = 0; h < 2; ++h) {
                bf16x8 bb = *reinterpret_cast<const bf16x8*>(&u.s.B[h][lg][kb0 + (kf << 4) + lr][0]);
#pragma unroll
                for (int tf = 0; tf < 4; ++tf)
                    acc[kf][tf] = __builtin_amdgcn_mfma_f32_16x16x32_bf16(a[tf][h], bb, acc[kf][tf], 0, 0, 0);
            }
        }
        __syncthreads();   // compute done before next overwrite
    }

    // inverse norms (thread pair t^1 holds the complementary d-half)
    sq += __shfl_xor(sq, 1, 64);
    if ((t & 1) == 0) inv_s[tokS] = 1.0f / sqrtf(sq);
    __syncthreads();

    float iv[4][4];
#pragma unroll
    for (int tf = 0; tf < 4; ++tf)
#pragma unroll
        for (int r = 0; r < 4; ++r)
            iv[tf][r] = inv_s[tok0 + (tf << 4) + (lg << 2) + r];

    // exp (bounded logits, no max-subtract) + per-token partial sums over this wave's 128 K
    float rowsum[4][4];
#pragma unroll
    for (int tf = 0; tf < 4; ++tf)
#pragma unroll
        for (int r = 0; r < 4; ++r) rowsum[tf][r] = 0.f;
#pragma unroll
    for (int kf = 0; kf < 8; ++kf)
#pragma unroll
        for (int tf = 0; tf < 4; ++tf)
#pragma unroll
            for (int r = 0; r < 4; ++r) {
                float e = __expf(acc[kf][tf][r] * iv[tf][r]);
                acc[kf][tf][r] = e; rowsum[tf][r] += e;
            }
#pragma unroll
    for (int tf = 0; tf < 4; ++tf)
#pragma unroll
        for (int r = 0; r < 4; ++r) {
#pragma unroll
            for (int m = 1; m < 16; m <<= 1) rowsum[tf][r] += __shfl_xor(rowsum[tf][r], m, 64);
        }
    if (lr == 0) {
#pragma unroll
        for (int tf = 0; tf < 4; ++tf)
#pragma unroll
            for (int r = 0; r < 4; ++r)
                ksum[wk][tok0 + (tf << 4) + (lg << 2) + r] = rowsum[tf][r];
    }
    __syncthreads();

    float rs[4][4];
#pragma unroll
    for (int tf = 0; tf < 4; ++tf)
#pragma unroll
        for (int r = 0; r < 4; ++r) {
            int idx = tok0 + (tf << 4) + (lg << 2) + r;
            rs[tf][r] = 1.0f / (ksum[0][idx] + ksum[1][idx]);
        }

    // prob, den column sums, transpose into LDS T[K][token]
    float dcol[8];
#pragma unroll
    for (int kf = 0; kf < 8; ++kf) dcol[kf] = 0.f;
#pragma unroll
    for (int kf = 0; kf < 8; ++kf)
#pragma unroll
        for (int tf = 0; tf < 4; ++tf)
#pragma unroll
            for (int r = 0; r < 4; ++r) {
                float p = acc[kf][tf][r] * rs[tf][r];
                acc[kf][tf][r] = p; dcol[kf] += p;
            }
#pragma unroll
    for (int kf = 0; kf < 8; ++kf) {
        dcol[kf] += __shfl_xor(dcol[kf], 16, 64);
        dcol[kf] += __shfl_xor(dcol[kf], 32, 64);
    }
    if (lg == 0) {
#pragma unroll
        for (int kf = 0; kf < 8; ++kf) atomicAdd(&denp[kb0 + (kf << 4) + lr], dcol[kf]);
    }
#pragma unroll
    for (int kf = 0; kf < 8; ++kf)
#pragma unroll
        for (int tf = 0; tf < 4; ++tf)
            *reinterpret_cast<ushort4*>(&u.T[kb0 + (kf << 4) + lr][tok0 + (tf << 4) + (lg << 2)]) =
                make_ushort4(f2bf(acc[kf][tf][0]), f2bf(acc[kf][tf][1]),
                             f2bf(acc[kf][tf][2]), f2bf(acc[kf][tf][3]));
    __syncthreads();

    // coalesced writeout of probT tile [256][128]
    u16* pTb = probT + (size_t)b * 256 * 8192 + n0;
#pragma unroll
    for (int i = 0; i < 16; ++i) {
        int idx = (i << 8) + t;
        int row = idx >> 4, ch = idx & 15;
        *reinterpret_cast<uint4*>(pTb + (size_t)row * 8192 + (ch << 3)) =
            *reinterpret_cast<const uint4*>(&u.T[row][ch << 3]);
    }
    atomicAdd(&den[(b << 8) + t], denp[t]);
}

// ---------- GEMM2+finalize fused (R15-exact): out += acc/(den+eps) via native f32 atomics ----------
__global__ __launch_bounds__(256) void k_gemm2(const float* __restrict__ x, const u16* __restrict__ probT,
                                               const float* __restrict__ den, float* __restrict__ out) {
    const int bid = blockIdx.x;                // 768 blocks
    const int xcd = bid & 7, slot = bid >> 3;
    const int orig = xcd * 96 + slot;
    const int dt = orig % 12, sb = orig / 12;  // 12 d-tiles of one (s,b) share an XCD
    const int s = sb >> 3, b = sb & 7;
    const int d0 = dt << 6;
    const int t = threadIdx.x;
    const int wave = t >> 6, lane = t & 63;
    const int lg = lane >> 4, lr = lane & 15;

    f32x4 acc[4][4];
#pragma unroll
    for (int m = 0; m < 4; ++m)
#pragma unroll
        for (int tt = 0; tt < 4; ++tt) acc[m][tt] = (f32x4){0.f, 0.f, 0.f, 0.f};

    const int n0 = s << 10;
    const u16* pA = probT + (size_t)b * 256 * 8192;
    const float* xB = x + (size_t)b * 8192 * 768;

    for (int kb = 0; kb < 32; ++kb) {
        int nbase = n0 + (kb << 5);
        bf16x8 a[4];
#pragma unroll
        for (int m = 0; m < 4; ++m) {
            int k = (wave << 6) + (m << 4) + lr;
            a[m] = *reinterpret_cast<const bf16x8*>(pA + (size_t)k * 8192 + nbase + (lg << 3));
        }
        const float* xr = xB + (size_t)(nbase + (lg << 3)) * 768 + d0 + lr;
        bf16x8 bb[4];
#pragma unroll
        for (int tt = 0; tt < 4; ++tt)
#pragma unroll
            for (int j = 0; j < 8; ++j) {
                float f = xr[(size_t)j * 768 + (tt << 4)];
                bb[tt][j] = (short)f2bf(f);
            }
#pragma unroll
        for (int m = 0; m < 4; ++m)
#pragma unroll
            for (int tt = 0; tt < 4; ++tt)
                acc[m][tt] = __builtin_amdgcn_mfma_f32_16x16x32_bf16(a[m], bb[tt], acc[m][tt], 0, 0, 0);
    }

    // fused epilogue: scale by 1/(den+eps), accumulate into out with HW f32 atomics
    float* ob = out + (size_t)(b << 8) * 768;
#pragma unroll
    for (int m = 0; m < 4; ++m) {
        int kb_ = (wave << 6) + (m << 4) + (lg << 2);
#pragma unroll
        for (int reg = 0; reg < 4; ++reg) {
            float dv = 1.0f / (den[(b << 8) + kb_ + reg] + 1e-8f);
#pragma unroll
            for (int tt = 0; tt < 4; ++tt)
                unsafeAtomicAdd(&ob[(size_t)(kb_ + reg) * 768 + d0 + (tt << 4) + lr],
                                acc[m][tt][reg] * dv);
        }
    }
}

extern "C" void kernel_launch(void* const* d_in, const int* in_sizes, int n_in,
                              void* d_out, int out_size, void* d_ws, size_t ws_size,
                              hipStream_t stream) {
    const float* x = (const float*)d_in[0];
    const float* centers = (const float*)d_in[1];
    float* out = (float*)d_out;
    char* ws = (char*)d_ws;
    u16* cn       = (u16*)ws;                    //  3,145,728 B
    u16* probT    = (u16*)(ws + 3145728);        // 33,554,432 B
    float* den    = (float*)(ws + 36700160);     //      8,192 B  (total ~37 MB)

    k_centers<<<512, 256, 0, stream>>>(centers, cn, den, out);
    k_gemm1<<<dim3(64, 8), 256, 0, stream>>>(x, cn, probT, den);
    k_gemm2<<<768, 256, 0, stream>>>(x, probT, den, out);
}